// Round 8
// baseline (336.646 us; speedup 1.0000x reference)
//
#include <hip/hip_runtime.h>
#include <hip/hip_bf16.h>
#include <stdint.h>

// LSTM cell, fp32 I/O, GEMM via bf16 MFMA -- SINGLE fused kernel (no workspace).
//   gates[b,4H] = [x|h] @ W_stacked^T + b ; per-element LSTM combine, fp32 out.
// B=8192, I=H=1024, C=2048.
//
// Round 13: rounds 8-12 proved the GEMM schedule is NOT the limiter (four
// different schedules all 157-161us / MfmaUtil 38%).  The ~150us of the 307us
// total OUTSIDE the GEMM (cvt pass + workspace round-trip of 144MB) is the
// larger target.  This round: fuse fp32->bf16 conversion INTO the GEMM via
// reg-staging (T14: global fp32 load -> cvt in reg -> swizzled ds_write_b128),
// one half-tile per phase, write lagging load by one phase (rA/rB parity).
// Schedule geometry, LDS layout, XOR swizzle, asm frag reads, MFMA order and
// epilogue are identical to the verified round-8/12 kernels.
// Staging ledger (buffer pO=u&1, qO=u+1):
//   P1: load A1(u+1)->rB ; write rA=B1(u+1)->qO   (rA loaded at u-1.P4)
//   P2: load A0(u+2)->rA ; write rB=A1(u+1)->qO
//   P3: load B0(u+2)->rB ; write rA=A0(u+2)->pO
//   P4: load B1(u+2)->rA ; write rB=B0(u+2)->pO
// RAW: every half written >=2 phases before first read (A0/B0 one tile early,
// B1 read u+1.P2 written u.P1, A1 read u+1.P3 written u.P2).
// WAR: every region written >=2 barriers after its last read (A0/B0 last read
// u.P1, written u.P3/P4; qO regions last read in tile u-1).
// C++ loads/writes: compiler inserts exact counted vmcnt before each cvt;
// "memory"-clobbered asm fences pin loads early (cannot sink past lgkmcnt(0)).

typedef __bf16 bf16x8 __attribute__((ext_vector_type(8)));
typedef float f32x4 __attribute__((ext_vector_type(4)));

#define B_DIM 8192
#define H_DIM 1024
#define C_DIM 2048
#define W_ELEMS (H_DIM * C_DIM)

// Opaque LDS read; completion enforced by explicit lgkmcnt + sched_barrier.
__device__ __forceinline__ bf16x8 lds_read16(const void* p) {
    bf16x8 r;
    asm volatile("ds_read_b128 %0, %1"
                 : "=v"(r)
                 : "v"((const __attribute__((address_space(3))) void*)p));
    return r;
}

// ---------------- fused 256x256 GEMM (reg-staged fp32->bf16) + LSTM ----------------
__global__ __launch_bounds__(512, 2)
void lstm_fused256(const float* __restrict__ x, const float* __restrict__ h,
                   const float* __restrict__ Wi, const float* __restrict__ Wf,
                   const float* __restrict__ Wo, const float* __restrict__ Wg,
                   const float* __restrict__ c,
                   const float* __restrict__ pbi, const float* __restrict__ pbf,
                   const float* __restrict__ pbo, const float* __restrict__ pbg,
                   float* __restrict__ out)
{
    // [buf][A=0/B=1][row 0..255][col 0..63] bf16 = 128 KB
    __shared__ __hip_bfloat16 lds[2][2][256][64];
    char* const ldsBase = (char*)&lds[0][0][0][0];

    const int tid  = threadIdx.x;
    const int lane = tid & 63;
    const int wave = tid >> 6;        // 0..7
    const int wr   = wave >> 2;       // 0..1 (M)
    const int wc   = wave & 3;        // 0..3 (N)
    const int quad = lane >> 4;
    const int l16  = lane & 15;

    // XCD-aware swizzle: 512 blocks -> 64-block contiguous chunk per XCD.
    const int bid = (int)blockIdx.x;
    const int swz = (bid & 7) * 64 + (bid >> 3);
    const int m_base = (swz >> 4) * 256;   // 32 m-blocks
    const int n0     = (swz & 15) * 64;    // 16 n-blocks

    // ---- staging addresses (same row/sch mapping as the verified DMA kernel) ----
    uint32_t aOffF[2][2];               // [half][a] element offsets into x/h
    const float* Wp[2][2];              // [half][a] gate-baked fp32 W pointers
    uint32_t dstOff[2];                 // [a] LDS byte offset within a region
#pragma unroll
    for (int a = 0; a < 2; ++a) {
        const int li  = a * 512 + tid;
        const int row = li >> 3;           // 0..127
        const int sch = ((li & 7) ^ (row & 7)) * 8;   // XOR-swizzled source chunk
        dstOff[a] = (uint32_t)li * 16u;
#pragma unroll
        for (int hh = 0; hh < 2; ++hh) {
            aOffF[hh][a] = (uint32_t)(m_base + hh * 128 + row) * H_DIM + (uint32_t)sch;
            const int g   = (hh << 1) | ((row >> 4) & 1);
            const int hco = ((row >> 5) << 4) | (row & 15);
            const float* Wsel = (g == 0) ? Wi : (g == 1) ? Wf : (g == 2) ? Wo : Wg;
            Wp[hh][a] = Wsel + (size_t)(n0 + hco) * C_DIM + sch;
        }
    }

    f32x4 rA[4], rB[4];   // staging ping-pong: one half-tile (16 f32/thread) each

#define LOAD_A(REG, hh, SRC, KEL) do {                                              \
    _Pragma("unroll")                                                               \
    for (int a_ = 0; a_ < 2; ++a_) {                                                \
        REG[a_ * 2]     = *(const f32x4*)((SRC) + aOffF[hh][a_] + (KEL));           \
        REG[a_ * 2 + 1] = *(const f32x4*)((SRC) + aOffF[hh][a_] + (KEL) + 4);       \
    } } while (0)
#define LOAD_B(REG, hh, KEL) do {                                                   \
    _Pragma("unroll")                                                               \
    for (int a_ = 0; a_ < 2; ++a_) {                                                \
        REG[a_ * 2]     = *(const f32x4*)(Wp[hh][a_] + (KEL));                      \
        REG[a_ * 2 + 1] = *(const f32x4*)(Wp[hh][a_] + (KEL) + 4);                  \
    } } while (0)
#define WRITE_HALF(REG, BUFO, REGION) do {                                          \
    _Pragma("unroll")                                                               \
    for (int a_ = 0; a_ < 2; ++a_) {                                                \
        __hip_bfloat16 t_[8];                                                       \
        t_[0] = __float2bfloat16(REG[a_*2][0]);  t_[1] = __float2bfloat16(REG[a_*2][1]); \
        t_[2] = __float2bfloat16(REG[a_*2][2]);  t_[3] = __float2bfloat16(REG[a_*2][3]); \
        t_[4] = __float2bfloat16(REG[a_*2+1][0]); t_[5] = __float2bfloat16(REG[a_*2+1][1]); \
        t_[6] = __float2bfloat16(REG[a_*2+1][2]); t_[7] = __float2bfloat16(REG[a_*2+1][3]); \
        *(bf16x8*)(ldsBase + (BUFO) + (REGION) + dstOff[a_]) = *(const bf16x8*)t_;  \
    } } while (0)
#define WRITE_A(REG, BUFO, hh) WRITE_HALF(REG, BUFO, (uint32_t)(hh) * 16384u)
#define WRITE_B(REG, BUFO, hh) WRITE_HALF(REG, BUFO, 32768u + (uint32_t)(hh) * 16384u)

    // ---- fragment read bases (unchanged) ----
    const uint32_t cb    = (uint32_t)((quad ^ (l16 & 7)) * 16);
    const uint32_t aBase = (uint32_t)(wr * 64 + l16) * 128u + cb;            // A region
    const uint32_t bBase = 32768u + (uint32_t)(wc * 32 + l16) * 128u + cb;   // B region

#define LDA(dstv, pO, ihh, ii, ss) \
    dstv = lds_read16(ldsBase + (pO) + ((aBase + (ihh) * 16384u + (ii) * 2048u) ^ ((uint32_t)(ss) << 6)))
#define LDB(dstv, pO, jj, ss) \
    dstv = lds_read16(ldsBase + (pO) + ((bBase + (((jj) >> 1)) * 16384u + ((jj) & 1) * 2048u) ^ ((uint32_t)(ss) << 6)))

#define MFMA_Q(AV, BV, IOFF, JOFF) do {                                                   \
    _Pragma("unroll")                                                                     \
    for (int i = 0; i < 4; ++i)                                                           \
        _Pragma("unroll")                                                                 \
        for (int j = 0; j < 2; ++j)                                                       \
            acc[i + (IOFF)][j + (JOFF)] = __builtin_amdgcn_mfma_f32_16x16x32_bf16(        \
                AV[i][0], BV[j][0], acc[i + (IOFF)][j + (JOFF)], 0, 0, 0);                \
    _Pragma("unroll")                                                                     \
    for (int i = 0; i < 4; ++i)                                                           \
        _Pragma("unroll")                                                                 \
        for (int j = 0; j < 2; ++j)                                                       \
            acc[i + (IOFF)][j + (JOFF)] = __builtin_amdgcn_mfma_f32_16x16x32_bf16(        \
                AV[i][1], BV[j][1], acc[i + (IOFF)][j + (JOFF)], 0, 0, 0);                \
} while (0)

    f32x4 acc[8][4];
#pragma unroll
    for (int i = 0; i < 8; ++i)
#pragma unroll
        for (int j = 0; j < 4; ++j)
            acc[i][j] = (f32x4){0.f, 0.f, 0.f, 0.f};

    // ---- prologue: stage t0{A0,B0,A1,B1}, t1{A0,B0}; leave B1(1) in rA ----
    LOAD_A(rA, 0, x, 0u);                      // A0(0)
    LOAD_B(rB, 0, 0u);                         // B0(0)
    WRITE_A(rA, 0u, 0);  LOAD_A(rA, 1, x, 0u);    // A1(0)
    WRITE_B(rB, 0u, 0);  LOAD_B(rB, 1, 0u);       // B1(0)
    WRITE_A(rA, 0u, 1);  LOAD_A(rA, 0, x, 64u);   // A0(1)
    WRITE_B(rB, 0u, 1);  LOAD_B(rB, 0, 64u);      // B0(1)
    WRITE_A(rA, 65536u, 0);
    WRITE_B(rB, 65536u, 0);
    LOAD_B(rA, 1, 64u);                        // B1(1) -> rA (written at u=0.P1)
    asm volatile("s_waitcnt lgkmcnt(0)" ::: "memory");
    __builtin_amdgcn_s_barrier();

    bf16x8 av[4][2], bv0[2][2], bv1[2][2];

    for (int u = 0; u < 32; ++u) {
        const uint32_t pO = (uint32_t)(u & 1) * 65536u;   // tile u's buffer
        const uint32_t qO = pO ^ 65536u;                  // tile u+1's buffer
        const float* aS1 = (u + 1 < 16) ? x : h;
        const uint32_t ak1 = (uint32_t)((u + 1) & 15) * 64u;
        const float* aS2 = (u + 2 < 16) ? x : h;
        const uint32_t ak2 = (uint32_t)((u + 2) & 15) * 64u;
        const uint32_t bk2 = (uint32_t)(u + 2) * 64u;

        // ---- P1: MFMA A0xB0 ; load A1(u+1)->rB ; write rA=B1(u+1)->qO ----
#pragma unroll
        for (int i = 0; i < 4; ++i) { LDA(av[i][0], pO, 0, i, 0); LDA(av[i][1], pO, 0, i, 1); }
        LDB(bv0[0][0], pO, 0, 0); LDB(bv0[1][0], pO, 1, 0);
        LDB(bv0[0][1], pO, 0, 1); LDB(bv0[1][1], pO, 1, 1);
        if (u < 31) { LOAD_A(rB, 1, aS1, ak1); WRITE_B(rA, qO, 1); }
        __builtin_amdgcn_s_barrier();
        asm volatile("s_waitcnt lgkmcnt(0)" ::: "memory");
        __builtin_amdgcn_sched_barrier(0);
        __builtin_amdgcn_s_setprio(1);
        MFMA_Q(av, bv0, 0, 0);
        __builtin_amdgcn_s_setprio(0);
        __builtin_amdgcn_s_barrier();

        // ---- P2: MFMA A0xB1 ; load A0(u+2)->rA ; write rB=A1(u+1)->qO ----
        LDB(bv1[0][0], pO, 2, 0); LDB(bv1[1][0], pO, 3, 0);
        LDB(bv1[0][1], pO, 2, 1); LDB(bv1[1][1], pO, 3, 1);
        if (u < 30) LOAD_A(rA, 0, aS2, ak2);
        if (u < 31) WRITE_A(rB, qO, 1);
        __builtin_amdgcn_s_barrier();
        asm volatile("s_waitcnt lgkmcnt(0)" ::: "memory");
        __builtin_amdgcn_sched_barrier(0);
        __builtin_amdgcn_s_setprio(1);
        MFMA_Q(av, bv1, 0, 2);
        __builtin_amdgcn_s_setprio(0);
        __builtin_amdgcn_s_barrier();

        // ---- P3: MFMA A1xB0 ; load B0(u+2)->rB ; write rA=A0(u+2)->pO ----
#pragma unroll
        for (int i = 0; i < 4; ++i) { LDA(av[i][0], pO, 1, i, 0); LDA(av[i][1], pO, 1, i, 1); }
        if (u < 30) { LOAD_B(rB, 0, bk2); WRITE_A(rA, pO, 0); }
        __builtin_amdgcn_s_barrier();
        asm volatile("s_waitcnt lgkmcnt(0)" ::: "memory");
        __builtin_amdgcn_sched_barrier(0);
        __builtin_amdgcn_s_setprio(1);
        MFMA_Q(av, bv0, 4, 0);
        __builtin_amdgcn_s_setprio(0);
        __builtin_amdgcn_s_barrier();

        // ---- P4: MFMA A1xB1 ; load B1(u+2)->rA ; write rB=B0(u+2)->pO ----
        if (u < 30) { LOAD_B(rA, 1, bk2); WRITE_B(rB, pO, 0); }
        __builtin_amdgcn_s_barrier();
        asm volatile("s_waitcnt lgkmcnt(0)" ::: "memory");
        __builtin_amdgcn_sched_barrier(0);
        __builtin_amdgcn_s_setprio(1);
        MFMA_Q(av, bv1, 4, 2);
        __builtin_amdgcn_s_setprio(0);
        __builtin_amdgcn_s_barrier();
    }

#undef LOAD_A
#undef LOAD_B
#undef WRITE_HALF
#undef WRITE_A
#undef WRITE_B
#undef LDA
#undef LDB
#undef MFMA_Q

    // ---- epilogue: per-lane LSTM combine (j == gate) ----
    const int col = n0 + wc * 16 + l16;
    const float vbi = pbi[col];
    const float vbf = pbf[col];
    const float vbo = pbo[col];
    const float vbg = pbg[col];
    const size_t HB = (size_t)B_DIM * H_DIM;
#pragma unroll
    for (int i = 0; i < 8; ++i) {
        const int fb  = (i < 4) ? (wr * 64 + i * 16) : (128 + wr * 64 + (i - 4) * 16);
        const int mb0 = m_base + fb + quad * 4;
#pragma unroll
        for (int r = 0; r < 4; ++r) {
            const size_t m = (size_t)(mb0 + r);
            const float ip = acc[i][0][r] + vbi;
            const float fp = acc[i][1][r] + vbf;
            const float op = acc[i][2][r] + vbo;
            const float gp = acc[i][3][r] + vbg;
            const float ig = 1.f / (1.f + __expf(-ip));
            const float fg = 1.f / (1.f + __expf(-fp));
            const float og = 1.f / (1.f + __expf(-op));
            const float eg = __expf(-2.f * fabsf(gp));
            const float gg = copysignf((1.f - eg) / (1.f + eg), gp);
            const float cin = c[m * H_DIM + col];
            const float ct = fg * cin + ig * gg;
            const float ec = __expf(-2.f * fabsf(ct));
            const float tc = copysignf((1.f - ec) / (1.f + ec), ct);
            out[m * H_DIM + col]      = og * tc;
            out[HB + m * H_DIM + col] = ct;
        }
    }
}

extern "C" void kernel_launch(void* const* d_in, const int* in_sizes, int n_in,
                              void* d_out, int out_size, void* d_ws, size_t ws_size,
                              hipStream_t stream) {
    const float* x  = (const float*)d_in[0];
    const float* h  = (const float*)d_in[1];
    const float* c  = (const float*)d_in[2];
    const float* Wi = (const float*)d_in[3];
    const float* Wf = (const float*)d_in[4];
    const float* Wo = (const float*)d_in[5];
    const float* Wg = (const float*)d_in[6];
    const float* bi = (const float*)d_in[7];
    const float* bfp= (const float*)d_in[8];
    const float* bo = (const float*)d_in[9];
    const float* bg = (const float*)d_in[10];
    float* out = (float*)d_out;
    (void)d_ws; (void)ws_size;

    lstm_fused256<<<512, 512, 0, stream>>>(
        x, h, Wi, Wf, Wo, Wg, c, bi, bfp, bo, bg, out);
}

// Round 9
// 326.961 us; speedup vs baseline: 1.0296x; 1.0296x over previous
//
#include <hip/hip_runtime.h>
#include <hip/hip_bf16.h>
#include <stdint.h>

// LSTM cell, fp32 I/O, GEMM via bf16 MFMA.
//   gates[b, 4H] = [x|h] @ W_stacked^T + b ; per-element LSTM combine, fp32 out.
// B=8192, I=H=1024, C=2048.
//
// Round 14: REVERT to the best-measured GEMM (round-0 128x128/BK=64 kernel,
// 151us) with ONE change: __launch_bounds__(256,3) -> (256,4).
// Rationale: round-13's single-kernel run isolated ~115us FIXED harness
// overhead (total-dispatch gap with no cvt present); cvt is only ~30us.
// Six GEMM schedule variants (8-phase, opaque reads, k-split, derived waits,
// fused) all land 151-161us -> schedule is not the lever.  The untouched
// first-order variable is occupancy: 32KB LDS + 84 VGPR admit 4 blocks/CU
// (128KB LDS, 4 waves/SIMD, VGPR cap 128).  Independent resident blocks
// overlap each other's per-K-step vmcnt(0) barrier drains (m114) -- the
// documented m97-plateau stall.  cvt: grid-stride bf16x8 (measured fine).

typedef __bf16 bf16x8 __attribute__((ext_vector_type(8)));
typedef __bf16 bf16x4 __attribute__((ext_vector_type(4)));
typedef float f32x4 __attribute__((ext_vector_type(4)));

#define B_DIM 8192
#define H_DIM 1024
#define C_DIM 2048
#define BM 128
#define BNC 32               // output columns (per gate) per block
#define BK 64
#define K_ITERS (C_DIM / BK) // 32

#define XH_ELEMS (B_DIM * H_DIM)               // 8388608
#define W_ELEMS  (H_DIM * C_DIM)               // 2097152
#define CVT_TOTAL (2 * XH_ELEMS + 4 * W_ELEMS) // 25165824 floats
#define WS_NEEDED ((size_t)CVT_TOTAL * 2)      // 50331648 bytes of bf16

__device__ __forceinline__ void async_cp16(void* lds_dst, const void* g_src) {
    __builtin_amdgcn_global_load_lds(
        (const __attribute__((address_space(1))) void*)g_src,
        (__attribute__((address_space(3))) void*)lds_dst,
        16, 0, 0);
}

// ---------------- fp32 -> bf16 bulk convert (pass 1) ----------------
__global__ __launch_bounds__(256)
void cvt_kernel(const float* __restrict__ x, const float* __restrict__ h,
                const float* __restrict__ wi, const float* __restrict__ wf,
                const float* __restrict__ wo, const float* __restrict__ wg,
                __hip_bfloat16* __restrict__ dst)
{
    const size_t stride = (size_t)gridDim.x * 256;
    for (size_t t = (size_t)blockIdx.x * 256 + threadIdx.x;
         t < (size_t)(CVT_TOTAL / 8); t += stride) {
        const size_t base = t * 8;
        const float* src;
        size_t off;
        if (base < (size_t)XH_ELEMS)            { src = x; off = base; }
        else if (base < (size_t)2 * XH_ELEMS)   { src = h; off = base - XH_ELEMS; }
        else {
            const size_t wb = base - (size_t)2 * XH_ELEMS;
            const int g = (int)(wb >> 21);          // W_ELEMS = 2^21
            off = wb & (size_t)(W_ELEMS - 1);
            src = (g == 0) ? wi : (g == 1) ? wf : (g == 2) ? wo : wg;
        }
        const f32x4 v0 = *(const f32x4*)(src + off);
        const f32x4 v1 = *(const f32x4*)(src + off + 4);
        __hip_bfloat16 tmp[8];
        tmp[0] = __float2bfloat16(v0[0]); tmp[1] = __float2bfloat16(v0[1]);
        tmp[2] = __float2bfloat16(v0[2]); tmp[3] = __float2bfloat16(v0[3]);
        tmp[4] = __float2bfloat16(v1[0]); tmp[5] = __float2bfloat16(v1[1]);
        tmp[6] = __float2bfloat16(v1[2]); tmp[7] = __float2bfloat16(v1[3]);
        *(bf16x8*)(dst + base) = *(const bf16x8*)tmp;
    }
}

// ---------------- GEMM + LSTM epilogue ----------------
__global__ __launch_bounds__(256, 4)
void lstm_gemm_bf16(const __hip_bfloat16* __restrict__ xb,
                    const __hip_bfloat16* __restrict__ hb,
                    const __hip_bfloat16* __restrict__ Wb,   // [4][H][C]
                    const float* __restrict__ c,
                    const float* __restrict__ pbi, const float* __restrict__ pbf,
                    const float* __restrict__ pbo, const float* __restrict__ pbg,
                    float* __restrict__ out)
{
    __shared__ __hip_bfloat16 As[BM][BK];   // 16 KB, XOR-swizzled chunks
    __shared__ __hip_bfloat16 Bs[BM][BK];   // 16 KB, gate-interleaved + swizzled

    const int tid  = threadIdx.x;
    const int lane = tid & 63;
    const int wave = tid >> 6;
    const int wr   = wave >> 1;
    const int wc   = wave & 1;
    const int quad = lane >> 4;
    const int l16  = lane & 15;

    const int m_base = blockIdx.y * BM;
    const int n0     = blockIdx.x * BNC;

    // staging: 4 issues x 256 threads x 16B = 16 KB per matrix.
    // li -> row = li>>3, dst chunk = li&7; SOURCE chunk = (li&7) ^ (row&7).
    const __hip_bfloat16* aSrc[4][2];
    const __hip_bfloat16* bSrc[4];
    char *aDst[4], *bDst[4];
#pragma unroll
    for (int a = 0; a < 4; ++a) {
        const int li   = a * 256 + tid;
        const int row  = li >> 3;
        const int sch  = ((li & 7) ^ (row & 7)) * 8;   // source element offset
        aSrc[a][0] = xb + (size_t)(m_base + row) * H_DIM + sch;
        aSrc[a][1] = hb + (size_t)(m_base + row) * H_DIM + sch;
        aDst[a]    = (char*)(&As[0][0]) + (size_t)li * 16;
        const int gate = (row >> 4) & 3;
        const int grow = n0 + ((row >> 6) << 4) + (row & 15);
        bSrc[a] = Wb + (size_t)gate * W_ELEMS + (size_t)grow * C_DIM + sch;
        bDst[a] = (char*)(&Bs[0][0]) + (size_t)li * 16;
    }

    int aRow[4], bRow[4];
#pragma unroll
    for (int i = 0; i < 4; ++i) aRow[i] = wr * 64 + i * 16 + l16;
#pragma unroll
    for (int j = 0; j < 4; ++j) bRow[j] = wc * 64 + j * 16 + l16;

    f32x4 acc[4][4];
#pragma unroll
    for (int i = 0; i < 4; ++i)
#pragma unroll
        for (int j = 0; j < 4; ++j)
            acc[i][j] = (f32x4){0.f, 0.f, 0.f, 0.f};

    for (int kt = 0; kt < K_ITERS; ++kt) {
        const int hsel = (kt >= (H_DIM / BK));   // 0: x-half, 1: h-half
        const int koff = (kt & ((H_DIM / BK) - 1)) * BK;
#pragma unroll
        for (int a = 0; a < 4; ++a)
            async_cp16(aDst[a], aSrc[a][hsel] + koff);
#pragma unroll
        for (int a = 0; a < 4; ++a)
            async_cp16(bDst[a], bSrc[a] + kt * BK);
        __syncthreads();   // drains vmcnt(0)

#pragma unroll
        for (int s = 0; s < 2; ++s) {
            bf16x8 av[4], bv[4];
#pragma unroll
            for (int i = 0; i < 4; ++i) {
                const int r  = aRow[i];
                const int ch = (s * 4 + quad) ^ (r & 7);
                av[i] = *(const bf16x8*)((const char*)&As[0][0] + r * (BK * 2) + ch * 16);
            }
#pragma unroll
            for (int j = 0; j < 4; ++j) {
                const int r  = bRow[j];
                const int ch = (s * 4 + quad) ^ (r & 7);
                bv[j] = *(const bf16x8*)((const char*)&Bs[0][0] + r * (BK * 2) + ch * 16);
            }
#pragma unroll
            for (int i = 0; i < 4; ++i)
#pragma unroll
                for (int j = 0; j < 4; ++j)
                    acc[i][j] = __builtin_amdgcn_mfma_f32_16x16x32_bf16(
                        av[i], bv[j], acc[i][j], 0, 0, 0);
        }
        __syncthreads();
    }

    // ---- epilogue: per-lane LSTM combine (j-tile == gate) ----
    const int col = n0 + wc * 16 + l16;
    const float vbi = pbi[col];
    const float vbf = pbf[col];
    const float vbo = pbo[col];
    const float vbg = pbg[col];
    const size_t HB = (size_t)B_DIM * H_DIM;
#pragma unroll
    for (int i = 0; i < 4; ++i) {
        const int mb = m_base + wr * 64 + i * 16 + quad * 4;
#pragma unroll
        for (int r = 0; r < 4; ++r) {
            const size_t m = (size_t)(mb + r);
            const float ip = acc[i][0][r] + vbi;
            const float fp = acc[i][1][r] + vbf;
            const float op = acc[i][2][r] + vbo;
            const float gp = acc[i][3][r] + vbg;
            const float ig = 1.f / (1.f + __expf(-ip));
            const float fg = 1.f / (1.f + __expf(-fp));
            const float og = 1.f / (1.f + __expf(-op));
            const float eg = __expf(-2.f * fabsf(gp));
            const float gg = copysignf((1.f - eg) / (1.f + eg), gp);
            const float cin = c[m * H_DIM + col];
            const float ct = fg * cin + ig * gg;
            const float ec = __expf(-2.f * fabsf(ct));
            const float tc = copysignf((1.f - ec) / (1.f + ec), ct);
            out[m * H_DIM + col]      = og * tc;
            out[HB + m * H_DIM + col] = ct;
        }
    }
}

// ---------------- fallback: fused fp32-load path (small ws) ----------------
__global__ __launch_bounds__(256, 2)
void lstm_gemm_fused(const float* __restrict__ x, const float* __restrict__ h,
                     const float* __restrict__ Wi, const float* __restrict__ Wf,
                     const float* __restrict__ Wo, const float* __restrict__ Wg,
                     const float* __restrict__ c,
                     const float* __restrict__ pbi, const float* __restrict__ pbf,
                     const float* __restrict__ pbo, const float* __restrict__ pbg,
                     float* __restrict__ out)
{
    __shared__ __hip_bfloat16 As[BM][BK];
    __shared__ __hip_bfloat16 Bs[BM][BK];

    const int tid  = threadIdx.x;
    const int lane = tid & 63;
    const int wave = tid >> 6;
    const int wr   = wave >> 1;
    const int wc   = wave & 1;
    const int quad = lane >> 4;
    const int l16  = lane & 15;

    const int m_base = blockIdx.y * BM;
    const int n0     = blockIdx.x * BNC;

    const int srow = tid >> 1;
    const int scol = (tid & 1) * 32;
    const float* aS[2] = {
        x + (size_t)(m_base + srow) * H_DIM + scol,
        h + (size_t)(m_base + srow) * H_DIM + scol
    };
    const int gate = (srow >> 4) & 3;
    const int grow = n0 + ((srow >> 6) << 4) + (srow & 15);
    const float* Wsel = (gate == 0) ? Wi : (gate == 1) ? Wf : (gate == 2) ? Wo : Wg;
    const float* bS = Wsel + (size_t)grow * C_DIM + scol;

    int aRow[4], bRow[4];
#pragma unroll
    for (int i = 0; i < 4; ++i) aRow[i] = wr * 64 + i * 16 + l16;
#pragma unroll
    for (int j = 0; j < 4; ++j) bRow[j] = wc * 64 + j * 16 + l16;

    f32x4 acc[4][4];
#pragma unroll
    for (int i = 0; i < 4; ++i)
#pragma unroll
        for (int j = 0; j < 4; ++j)
            acc[i][j] = (f32x4){0.f, 0.f, 0.f, 0.f};

    for (int kt = 0; kt < K_ITERS; ++kt) {
        const int hsel = (kt >= (H_DIM / BK));
        const int koff = (kt & ((H_DIM / BK) - 1)) * BK;
        const float* ap = aS[hsel] + koff;
        const float* bp = bS + kt * BK;
        __hip_bfloat16 ta[32], tb[32];
#pragma unroll
        for (int q = 0; q < 8; ++q) {
            f32x4 a = *(const f32x4*)(ap + q * 4);
            f32x4 b = *(const f32x4*)(bp + q * 4);
            ta[q*4+0]=__float2bfloat16(a[0]); ta[q*4+1]=__float2bfloat16(a[1]);
            ta[q*4+2]=__float2bfloat16(a[2]); ta[q*4+3]=__float2bfloat16(a[3]);
            tb[q*4+0]=__float2bfloat16(b[0]); tb[q*4+1]=__float2bfloat16(b[1]);
            tb[q*4+2]=__float2bfloat16(b[2]); tb[q*4+3]=__float2bfloat16(b[3]);
        }
#pragma unroll
        for (int q = 0; q < 4; ++q) {
            const int ch  = (scol / 8) + q;
            const int sl  = ch ^ (srow & 7);
            *(bf16x8*)((char*)&As[0][0] + srow * (BK * 2) + sl * 16) = *(const bf16x8*)&ta[q * 8];
            *(bf16x8*)((char*)&Bs[0][0] + srow * (BK * 2) + sl * 16) = *(const bf16x8*)&tb[q * 8];
        }
        __syncthreads();

#pragma unroll
        for (int s = 0; s < 2; ++s) {
            bf16x8 av[4], bv[4];
#pragma unroll
            for (int i = 0; i < 4; ++i) {
                const int r  = aRow[i];
                const int ch = (s * 4 + quad) ^ (r & 7);
                av[i] = *(const bf16x8*)((const char*)&As[0][0] + r * (BK * 2) + ch * 16);
            }
#pragma unroll
            for (int j = 0; j < 4; ++j) {
                const int r  = bRow[j];
                const int ch = (s * 4 + quad) ^ (r & 7);
                bv[j] = *(const bf16x8*)((const char*)&Bs[0][0] + r * (BK * 2) + ch * 16);
            }
#pragma unroll
            for (int i = 0; i < 4; ++i)
#pragma unroll
                for (int j = 0; j < 4; ++j)
                    acc[i][j] = __builtin_amdgcn_mfma_f32_16x16x32_bf16(
                        av[i], bv[j], acc[i][j], 0, 0, 0);
        }
        __syncthreads();
    }

    const int col = n0 + wc * 16 + l16;
    const float vbi = pbi[col];
    const float vbf = pbf[col];
    const float vbo = pbo[col];
    const float vbg = pbg[col];
    const size_t HB = (size_t)B_DIM * H_DIM;
#pragma unroll
    for (int i = 0; i < 4; ++i) {
        const int mb = m_base + wr * 64 + i * 16 + quad * 4;
#pragma unroll
        for (int r = 0; r < 4; ++r) {
            const size_t m = (size_t)(mb + r);
            const float ip = acc[i][0][r] + vbi;
            const float fp = acc[i][1][r] + vbf;
            const float op = acc[i][2][r] + vbo;
            const float gp = acc[i][3][r] + vbg;
            const float ig = 1.f / (1.f + __expf(-ip));
            const float fg = 1.f / (1.f + __expf(-fp));
            const float og = 1.f / (1.f + __expf(-op));
            const float eg = __expf(-2.f * fabsf(gp));
            const float gg = copysignf((1.f - eg) / (1.f + eg), gp);
            const float cin = c[m * H_DIM + col];
            const float ct = fg * cin + ig * gg;
            const float ec = __expf(-2.f * fabsf(ct));
            const float tc = copysignf((1.f - ec) / (1.f + ec), ct);
            out[m * H_DIM + col]      = og * tc;
            out[HB + m * H_DIM + col] = ct;
        }
    }
}

extern "C" void kernel_launch(void* const* d_in, const int* in_sizes, int n_in,
                              void* d_out, int out_size, void* d_ws, size_t ws_size,
                              hipStream_t stream) {
    const float* x  = (const float*)d_in[0];
    const float* h  = (const float*)d_in[1];
    const float* c  = (const float*)d_in[2];
    const float* Wi = (const float*)d_in[3];
    const float* Wf = (const float*)d_in[4];
    const float* Wo = (const float*)d_in[5];
    const float* Wg = (const float*)d_in[6];
    const float* bi = (const float*)d_in[7];
    const float* bfp= (const float*)d_in[8];
    const float* bo = (const float*)d_in[9];
    const float* bg = (const float*)d_in[10];
    float* out = (float*)d_out;

    dim3 grid(H_DIM / BNC, B_DIM / BM);  // (32, 64) = 2048 blocks

    if (ws_size >= WS_NEEDED) {
        __hip_bfloat16* wsb = (__hip_bfloat16*)d_ws;
        cvt_kernel<<<2048, 256, 0, stream>>>(x, h, Wi, Wf, Wo, Wg, wsb);
        lstm_gemm_bf16<<<grid, dim3(256), 0, stream>>>(
            wsb, wsb + XH_ELEMS, wsb + 2 * (size_t)XH_ELEMS,
            c, bi, bfp, bo, bg, out);
    } else {
        lstm_gemm_fused<<<grid, dim3(256), 0, stream>>>(
            x, h, Wi, Wf, Wo, Wg, c, bi, bfp, bo, bg, out);
    }
}

// Round 10
// 317.780 us; speedup vs baseline: 1.0594x; 1.0289x over previous
//
#include <hip/hip_runtime.h>
#include <hip/hip_bf16.h>
#include <stdint.h>

// LSTM cell, fp32 I/O, GEMM via bf16 MFMA.
//   gates[b, 4H] = [x|h] @ W_stacked^T + b ; per-element LSTM combine, fp32 out.
// B=8192, I=H=1024, C=2048.
//
// Round 15: revert to the best-measured config (round-0 128x128/BK=64 GEMM at
// __launch_bounds__(256,3), GEMM ~151us) + ONE addition: bijective XCD-aware
// block swizzle (T1).  Round-14's (256,4) regression proved dur tracks
// staging L2-hit rate (FETCH 164->250MB <-> dur 151->169us): the per-K-step
// __syncthreads drains vmcnt(0), so drain time = latency of the slowest
// staged load (L2 ~200cy vs HBM ~900cy).  Default dispatch round-robins
// consecutive blocks across 8 XCDs -> the 32 n-blocks sharing an A-panel hit
// 8 different L2s.  Swizzle gives each XCD 256 contiguous linear blocks
// (8 complete m-rows; 2048%8==0 -> bijective) -> A-panel reuse is XCD-local.
// Predicted: FETCH 164->~100-130MB, GEMM -> 140-152us.  If FETCH drops but
// dur is flat -> kernel is issue-limited; declare practical ceiling.

typedef __bf16 bf16x8 __attribute__((ext_vector_type(8)));
typedef __bf16 bf16x4 __attribute__((ext_vector_type(4)));
typedef float f32x4 __attribute__((ext_vector_type(4)));

#define B_DIM 8192
#define H_DIM 1024
#define C_DIM 2048
#define BM 128
#define BNC 32               // output columns (per gate) per block
#define BK 64
#define K_ITERS (C_DIM / BK) // 32

#define XH_ELEMS (B_DIM * H_DIM)               // 8388608
#define W_ELEMS  (H_DIM * C_DIM)               // 2097152
#define CVT_TOTAL (2 * XH_ELEMS + 4 * W_ELEMS) // 25165824 floats
#define WS_NEEDED ((size_t)CVT_TOTAL * 2)      // 50331648 bytes of bf16

__device__ __forceinline__ void async_cp16(void* lds_dst, const void* g_src) {
    __builtin_amdgcn_global_load_lds(
        (const __attribute__((address_space(1))) void*)g_src,
        (__attribute__((address_space(3))) void*)lds_dst,
        16, 0, 0);
}

// ---------------- fp32 -> bf16 bulk convert (pass 1) ----------------
__global__ __launch_bounds__(256)
void cvt_kernel(const float* __restrict__ x, const float* __restrict__ h,
                const float* __restrict__ wi, const float* __restrict__ wf,
                const float* __restrict__ wo, const float* __restrict__ wg,
                __hip_bfloat16* __restrict__ dst)
{
    const size_t stride = (size_t)gridDim.x * 256;
    for (size_t t = (size_t)blockIdx.x * 256 + threadIdx.x;
         t < (size_t)(CVT_TOTAL / 8); t += stride) {
        const size_t base = t * 8;
        const float* src;
        size_t off;
        if (base < (size_t)XH_ELEMS)            { src = x; off = base; }
        else if (base < (size_t)2 * XH_ELEMS)   { src = h; off = base - XH_ELEMS; }
        else {
            const size_t wb = base - (size_t)2 * XH_ELEMS;
            const int g = (int)(wb >> 21);          // W_ELEMS = 2^21
            off = wb & (size_t)(W_ELEMS - 1);
            src = (g == 0) ? wi : (g == 1) ? wf : (g == 2) ? wo : wg;
        }
        const f32x4 v0 = *(const f32x4*)(src + off);
        const f32x4 v1 = *(const f32x4*)(src + off + 4);
        __hip_bfloat16 tmp[8];
        tmp[0] = __float2bfloat16(v0[0]); tmp[1] = __float2bfloat16(v0[1]);
        tmp[2] = __float2bfloat16(v0[2]); tmp[3] = __float2bfloat16(v0[3]);
        tmp[4] = __float2bfloat16(v1[0]); tmp[5] = __float2bfloat16(v1[1]);
        tmp[6] = __float2bfloat16(v1[2]); tmp[7] = __float2bfloat16(v1[3]);
        *(bf16x8*)(dst + base) = *(const bf16x8*)tmp;
    }
}

// ---------------- GEMM + LSTM epilogue ----------------
__global__ __launch_bounds__(256, 3)
void lstm_gemm_bf16(const __hip_bfloat16* __restrict__ xb,
                    const __hip_bfloat16* __restrict__ hb,
                    const __hip_bfloat16* __restrict__ Wb,   // [4][H][C]
                    const float* __restrict__ c,
                    const float* __restrict__ pbi, const float* __restrict__ pbf,
                    const float* __restrict__ pbo, const float* __restrict__ pbg,
                    float* __restrict__ out)
{
    __shared__ __hip_bfloat16 As[BM][BK];   // 16 KB, XOR-swizzled chunks
    __shared__ __hip_bfloat16 Bs[BM][BK];   // 16 KB, gate-interleaved + swizzled

    const int tid  = threadIdx.x;
    const int lane = tid & 63;
    const int wave = tid >> 6;
    const int wr   = wave >> 1;
    const int wc   = wave & 1;
    const int quad = lane >> 4;
    const int l16  = lane & 15;

    // XCD-aware bijective swizzle: linear id -> each XCD owns 256 contiguous
    // linear blocks (8 full m-rows of 32 n-blocks).  2048 % 8 == 0.
    const int lid = (int)(blockIdx.y * gridDim.x + blockIdx.x);
    const int swz = (lid & 7) * 256 + (lid >> 3);
    const int m_base = (swz >> 5) * BM;    // swz / 32
    const int n0     = (swz & 31) * BNC;   // swz % 32

    // staging: 4 issues x 256 threads x 16B = 16 KB per matrix.
    // li -> row = li>>3, dst chunk = li&7; SOURCE chunk = (li&7) ^ (row&7).
    const __hip_bfloat16* aSrc[4][2];
    const __hip_bfloat16* bSrc[4];
    char *aDst[4], *bDst[4];
#pragma unroll
    for (int a = 0; a < 4; ++a) {
        const int li   = a * 256 + tid;
        const int row  = li >> 3;
        const int sch  = ((li & 7) ^ (row & 7)) * 8;   // source element offset
        aSrc[a][0] = xb + (size_t)(m_base + row) * H_DIM + sch;
        aSrc[a][1] = hb + (size_t)(m_base + row) * H_DIM + sch;
        aDst[a]    = (char*)(&As[0][0]) + (size_t)li * 16;
        const int gate = (row >> 4) & 3;
        const int grow = n0 + ((row >> 6) << 4) + (row & 15);
        bSrc[a] = Wb + (size_t)gate * W_ELEMS + (size_t)grow * C_DIM + sch;
        bDst[a] = (char*)(&Bs[0][0]) + (size_t)li * 16;
    }

    int aRow[4], bRow[4];
#pragma unroll
    for (int i = 0; i < 4; ++i) aRow[i] = wr * 64 + i * 16 + l16;
#pragma unroll
    for (int j = 0; j < 4; ++j) bRow[j] = wc * 64 + j * 16 + l16;

    f32x4 acc[4][4];
#pragma unroll
    for (int i = 0; i < 4; ++i)
#pragma unroll
        for (int j = 0; j < 4; ++j)
            acc[i][j] = (f32x4){0.f, 0.f, 0.f, 0.f};

    for (int kt = 0; kt < K_ITERS; ++kt) {
        const int hsel = (kt >= (H_DIM / BK));   // 0: x-half, 1: h-half
        const int koff = (kt & ((H_DIM / BK) - 1)) * BK;
#pragma unroll
        for (int a = 0; a < 4; ++a)
            async_cp16(aDst[a], aSrc[a][hsel] + koff);
#pragma unroll
        for (int a = 0; a < 4; ++a)
            async_cp16(bDst[a], bSrc[a] + kt * BK);
        __syncthreads();   // drains vmcnt(0)

#pragma unroll
        for (int s = 0; s < 2; ++s) {
            bf16x8 av[4], bv[4];
#pragma unroll
            for (int i = 0; i < 4; ++i) {
                const int r  = aRow[i];
                const int ch = (s * 4 + quad) ^ (r & 7);
                av[i] = *(const bf16x8*)((const char*)&As[0][0] + r * (BK * 2) + ch * 16);
            }
#pragma unroll
            for (int j = 0; j < 4; ++j) {
                const int r  = bRow[j];
                const int ch = (s * 4 + quad) ^ (r & 7);
                bv[j] = *(const bf16x8*)((const char*)&Bs[0][0] + r * (BK * 2) + ch * 16);
            }
#pragma unroll
            for (int i = 0; i < 4; ++i)
#pragma unroll
                for (int j = 0; j < 4; ++j)
                    acc[i][j] = __builtin_amdgcn_mfma_f32_16x16x32_bf16(
                        av[i], bv[j], acc[i][j], 0, 0, 0);
        }
        __syncthreads();
    }

    // ---- epilogue: per-lane LSTM combine (j-tile == gate) ----
    const int col = n0 + wc * 16 + l16;
    const float vbi = pbi[col];
    const float vbf = pbf[col];
    const float vbo = pbo[col];
    const float vbg = pbg[col];
    const size_t HB = (size_t)B_DIM * H_DIM;
#pragma unroll
    for (int i = 0; i < 4; ++i) {
        const int mb = m_base + wr * 64 + i * 16 + quad * 4;
#pragma unroll
        for (int r = 0; r < 4; ++r) {
            const size_t m = (size_t)(mb + r);
            const float ip = acc[i][0][r] + vbi;
            const float fp = acc[i][1][r] + vbf;
            const float op = acc[i][2][r] + vbo;
            const float gp = acc[i][3][r] + vbg;
            const float ig = 1.f / (1.f + __expf(-ip));
            const float fg = 1.f / (1.f + __expf(-fp));
            const float og = 1.f / (1.f + __expf(-op));
            const float eg = __expf(-2.f * fabsf(gp));
            const float gg = copysignf((1.f - eg) / (1.f + eg), gp);
            const float cin = c[m * H_DIM + col];
            const float ct = fg * cin + ig * gg;
            const float ec = __expf(-2.f * fabsf(ct));
            const float tc = copysignf((1.f - ec) / (1.f + ec), ct);
            out[m * H_DIM + col]      = og * tc;
            out[HB + m * H_DIM + col] = ct;
        }
    }
}

// ---------------- fallback: fused fp32-load path (small ws) ----------------
__global__ __launch_bounds__(256, 2)
void lstm_gemm_fused(const float* __restrict__ x, const float* __restrict__ h,
                     const float* __restrict__ Wi, const float* __restrict__ Wf,
                     const float* __restrict__ Wo, const float* __restrict__ Wg,
                     const float* __restrict__ c,
                     const float* __restrict__ pbi, const float* __restrict__ pbf,
                     const float* __restrict__ pbo, const float* __restrict__ pbg,
                     float* __restrict__ out)
{
    __shared__ __hip_bfloat16 As[BM][BK];
    __shared__ __hip_bfloat16 Bs[BM][BK];

    const int tid  = threadIdx.x;
    const int lane = tid & 63;
    const int wave = tid >> 6;
    const int wr   = wave >> 1;
    const int wc   = wave & 1;
    const int quad = lane >> 4;
    const int l16  = lane & 15;

    const int lid = (int)(blockIdx.y * gridDim.x + blockIdx.x);
    const int swz = (lid & 7) * 256 + (lid >> 3);
    const int m_base = (swz >> 5) * BM;
    const int n0     = (swz & 31) * BNC;

    const int srow = tid >> 1;
    const int scol = (tid & 1) * 32;
    const float* aS[2] = {
        x + (size_t)(m_base + srow) * H_DIM + scol,
        h + (size_t)(m_base + srow) * H_DIM + scol
    };
    const int gate = (srow >> 4) & 3;
    const int grow = n0 + ((srow >> 6) << 4) + (srow & 15);
    const float* Wsel = (gate == 0) ? Wi : (gate == 1) ? Wf : (gate == 2) ? Wo : Wg;
    const float* bS = Wsel + (size_t)grow * C_DIM + scol;

    int aRow[4], bRow[4];
#pragma unroll
    for (int i = 0; i < 4; ++i) aRow[i] = wr * 64 + i * 16 + l16;
#pragma unroll
    for (int j = 0; j < 4; ++j) bRow[j] = wc * 64 + j * 16 + l16;

    f32x4 acc[4][4];
#pragma unroll
    for (int i = 0; i < 4; ++i)
#pragma unroll
        for (int j = 0; j < 4; ++j)
            acc[i][j] = (f32x4){0.f, 0.f, 0.f, 0.f};

    for (int kt = 0; kt < K_ITERS; ++kt) {
        const int hsel = (kt >= (H_DIM / BK));
        const int koff = (kt & ((H_DIM / BK) - 1)) * BK;
        const float* ap = aS[hsel] + koff;
        const float* bp = bS + kt * BK;
        __hip_bfloat16 ta[32], tb[32];
#pragma unroll
        for (int q = 0; q < 8; ++q) {
            f32x4 a = *(const f32x4*)(ap + q * 4);
            f32x4 b = *(const f32x4*)(bp + q * 4);
            ta[q*4+0]=__float2bfloat16(a[0]); ta[q*4+1]=__float2bfloat16(a[1]);
            ta[q*4+2]=__float2bfloat16(a[2]); ta[q*4+3]=__float2bfloat16(a[3]);
            tb[q*4+0]=__float2bfloat16(b[0]); tb[q*4+1]=__float2bfloat16(b[1]);
            tb[q*4+2]=__float2bfloat16(b[2]); tb[q*4+3]=__float2bfloat16(b[3]);
        }
#pragma unroll
        for (int q = 0; q < 4; ++q) {
            const int ch  = (scol / 8) + q;
            const int sl  = ch ^ (srow & 7);
            *(bf16x8*)((char*)&As[0][0] + srow * (BK * 2) + sl * 16) = *(const bf16x8*)&ta[q * 8];
            *(bf16x8*)((char*)&Bs[0][0] + srow * (BK * 2) + sl * 16) = *(const bf16x8*)&tb[q * 8];
        }
        __syncthreads();

#pragma unroll
        for (int s = 0; s < 2; ++s) {
            bf16x8 av[4], bv[4];
#pragma unroll
            for (int i = 0; i < 4; ++i) {
                const int r  = aRow[i];
                const int ch = (s * 4 + quad) ^ (r & 7);
                av[i] = *(const bf16x8*)((const char*)&As[0][0] + r * (BK * 2) + ch * 16);
            }
#pragma unroll
            for (int j = 0; j < 4; ++j) {
                const int r  = bRow[j];
                const int ch = (s * 4 + quad) ^ (r & 7);
                bv[j] = *(const bf16x8*)((const char*)&Bs[0][0] + r * (BK * 2) + ch * 16);
            }
#pragma unroll
            for (int i = 0; i < 4; ++i)
#pragma unroll
                for (int j = 0; j < 4; ++j)
                    acc[i][j] = __builtin_amdgcn_mfma_f32_16x16x32_bf16(
                        av[i], bv[j], acc[i][j], 0, 0, 0);
        }
        __syncthreads();
    }

    const int col = n0 + wc * 16 + l16;
    const float vbi = pbi[col];
    const float vbf = pbf[col];
    const float vbo = pbo[col];
    const float vbg = pbg[col];
    const size_t HB = (size_t)B_DIM * H_DIM;
#pragma unroll
    for (int i = 0; i < 4; ++i) {
        const int mb = m_base + wr * 64 + i * 16 + quad * 4;
#pragma unroll
        for (int r = 0; r < 4; ++r) {
            const size_t m = (size_t)(mb + r);
            const float ip = acc[i][0][r] + vbi;
            const float fp = acc[i][1][r] + vbf;
            const float op = acc[i][2][r] + vbo;
            const float gp = acc[i][3][r] + vbg;
            const float ig = 1.f / (1.f + __expf(-ip));
            const float fg = 1.f / (1.f + __expf(-fp));
            const float og = 1.f / (1.f + __expf(-op));
            const float eg = __expf(-2.f * fabsf(gp));
            const float gg = copysignf((1.f - eg) / (1.f + eg), gp);
            const float cin = c[m * H_DIM + col];
            const float ct = fg * cin + ig * gg;
            const float ec = __expf(-2.f * fabsf(ct));
            const float tc = copysignf((1.f - ec) / (1.f + ec), ct);
            out[m * H_DIM + col]      = og * tc;
            out[HB + m * H_DIM + col] = ct;
        }
    }
}

extern "C" void kernel_launch(void* const* d_in, const int* in_sizes, int n_in,
                              void* d_out, int out_size, void* d_ws, size_t ws_size,
                              hipStream_t stream) {
    const float* x  = (const float*)d_in[0];
    const float* h  = (const float*)d_in[1];
    const float* c  = (const float*)d_in[2];
    const float* Wi = (const float*)d_in[3];
    const float* Wf = (const float*)d_in[4];
    const float* Wo = (const float*)d_in[5];
    const float* Wg = (const float*)d_in[6];
    const float* bi = (const float*)d_in[7];
    const float* bfp= (const float*)d_in[8];
    const float* bo = (const float*)d_in[9];
    const float* bg = (const float*)d_in[10];
    float* out = (float*)d_out;

    dim3 grid(H_DIM / BNC, B_DIM / BM);  // (32, 64) = 2048 blocks

    if (ws_size >= WS_NEEDED) {
        __hip_bfloat16* wsb = (__hip_bfloat16*)d_ws;
        cvt_kernel<<<2048, 256, 0, stream>>>(x, h, Wi, Wf, Wo, Wg, wsb);
        lstm_gemm_bf16<<<grid, dim3(256), 0, stream>>>(
            wsb, wsb + XH_ELEMS, wsb + 2 * (size_t)XH_ELEMS,
            c, bi, bfp, bo, bg, out);
    } else {
        lstm_gemm_fused<<<grid, dim3(256), 0, stream>>>(
            x, h, Wi, Wf, Wo, Wg, c, bi, bfp, bo, bg, out);
    }
}

// Round 14
// 302.336 us; speedup vs baseline: 1.1135x; 1.0511x over previous
//
#include <hip/hip_runtime.h>
#include <hip/hip_bf16.h>
#include <stdint.h>

// LSTM cell, fp32 I/O, GEMM via bf16 MFMA.
//   gates[b, 4H] = [x|h] @ W_stacked^T + b ; per-element LSTM combine, fp32 out.
// B=8192, I=H=1024, C=2048.
//
// Round 19 (= round-16/17/18 resubmit; broker timeouts, never ran): exact
// reversion to the best-measured configuration (round-0 kernel: 302.7us prev
// session best; 306-313us this session).  Campaign evidence for the floor:
//  - NOT memory-bound: r15 doubled FETCH (164->330MB, 2.6TB/s) -> time flat.
//  - NOT compute-bound: MfmaUtil 38-42% across all variants.
//  - Schedule-invariant: six structures (8-phase counted vmcnt, opaque
//    ds_reads, k-split MFMA, derived waits, fused reg-staging, 256^2 tile)
//    all land 151-161us GEMM -> the m97-class plateau (~880 TF).
//  - Occupancy up (256,4): VGPR 84->64 squeeze + L2 thrash -> 169us. Worse.
//  - XCD swizzle: B-panel thrash (each XCD needs all 16MB W) -> worse.
//  - Fusion (no ws): 2x fp32 fetch -> 221us GEMM. Worse.
//  - Fixed harness overhead ~115us (isolated in r13's single-kernel run);
//    cvt ~30us at near-BW.  Optimizable kernel time ~188us; this config
//    delivers it.

typedef __bf16 bf16x8 __attribute__((ext_vector_type(8)));
typedef __bf16 bf16x4 __attribute__((ext_vector_type(4)));
typedef float f32x4 __attribute__((ext_vector_type(4)));

#define B_DIM 8192
#define H_DIM 1024
#define C_DIM 2048
#define BM 128
#define BNC 32               // output columns (per gate) per block
#define BK 64
#define K_ITERS (C_DIM / BK) // 32

#define XH_ELEMS (B_DIM * H_DIM)               // 8388608
#define W_ELEMS  (H_DIM * C_DIM)               // 2097152
#define CVT_TOTAL (2 * XH_ELEMS + 4 * W_ELEMS) // 25165824 floats
#define WS_NEEDED ((size_t)CVT_TOTAL * 2)      // 50331648 bytes of bf16

__device__ __forceinline__ void async_cp16(void* lds_dst, const void* g_src) {
    __builtin_amdgcn_global_load_lds(
        (const __attribute__((address_space(1))) void*)g_src,
        (__attribute__((address_space(3))) void*)lds_dst,
        16, 0, 0);
}

// ---------------- fp32 -> bf16 bulk convert (pass 1), coalesced ----------------
__global__ __launch_bounds__(256)
void cvt_kernel(const float* __restrict__ x, const float* __restrict__ h,
                const float* __restrict__ wi, const float* __restrict__ wf,
                const float* __restrict__ wo, const float* __restrict__ wg,
                __hip_bfloat16* __restrict__ dst)
{
    const size_t t = (size_t)blockIdx.x * 256 + threadIdx.x;
    const size_t base = t * 4;                 // 16B/lane, lane-contiguous
    const float* src;
    size_t off;
    if (base < (size_t)XH_ELEMS)            { src = x; off = base; }
    else if (base < (size_t)2 * XH_ELEMS)   { src = h; off = base - XH_ELEMS; }
    else {
        const size_t wb = base - (size_t)2 * XH_ELEMS;
        const int g = (int)(wb >> 21);          // W_ELEMS = 2^21
        off = wb & (W_ELEMS - 1);
        src = (g == 0) ? wi : (g == 1) ? wf : (g == 2) ? wo : wg;
    }
    const f32x4 v = *(const f32x4*)(src + off);
    __hip_bfloat16 tmp[4];
    tmp[0] = __float2bfloat16(v[0]);
    tmp[1] = __float2bfloat16(v[1]);
    tmp[2] = __float2bfloat16(v[2]);
    tmp[3] = __float2bfloat16(v[3]);
    *(bf16x4*)(dst + base) = *(const bf16x4*)tmp;
}

// ---------------- GEMM + LSTM epilogue ----------------
__global__ __launch_bounds__(256, 3)
void lstm_gemm_bf16(const __hip_bfloat16* __restrict__ xb,
                    const __hip_bfloat16* __restrict__ hb,
                    const __hip_bfloat16* __restrict__ Wb,   // [4][H][C]
                    const float* __restrict__ c,
                    const float* __restrict__ pbi, const float* __restrict__ pbf,
                    const float* __restrict__ pbo, const float* __restrict__ pbg,
                    float* __restrict__ out)
{
    __shared__ __hip_bfloat16 As[BM][BK];   // 16 KB, XOR-swizzled chunks
    __shared__ __hip_bfloat16 Bs[BM][BK];   // 16 KB, gate-interleaved + swizzled

    const int tid  = threadIdx.x;
    const int lane = tid & 63;
    const int wave = tid >> 6;
    const int wr   = wave >> 1;
    const int wc   = wave & 1;
    const int quad = lane >> 4;
    const int l16  = lane & 15;

    const int m_base = blockIdx.y * BM;
    const int n0     = blockIdx.x * BNC;

    // staging: 4 issues x 256 threads x 16B = 16 KB per matrix.
    // li -> row = li>>3, dst chunk = li&7; SOURCE chunk = (li&7) ^ (row&7).
    const __hip_bfloat16* aSrc[4][2];
    const __hip_bfloat16* bSrc[4];
    char *aDst[4], *bDst[4];
#pragma unroll
    for (int a = 0; a < 4; ++a) {
        const int li   = a * 256 + tid;
        const int row  = li >> 3;
        const int sch  = ((li & 7) ^ (row & 7)) * 8;   // source element offset
        aSrc[a][0] = xb + (size_t)(m_base + row) * H_DIM + sch;
        aSrc[a][1] = hb + (size_t)(m_base + row) * H_DIM + sch;
        aDst[a]    = (char*)(&As[0][0]) + (size_t)li * 16;
        const int gate = (row >> 4) & 3;
        const int grow = n0 + ((row >> 6) << 4) + (row & 15);
        bSrc[a] = Wb + (size_t)gate * W_ELEMS + (size_t)grow * C_DIM + sch;
        bDst[a] = (char*)(&Bs[0][0]) + (size_t)li * 16;
    }

    int aRow[4], bRow[4];
#pragma unroll
    for (int i = 0; i < 4; ++i) aRow[i] = wr * 64 + i * 16 + l16;
#pragma unroll
    for (int j = 0; j < 4; ++j) bRow[j] = wc * 64 + j * 16 + l16;

    f32x4 acc[4][4];
#pragma unroll
    for (int i = 0; i < 4; ++i)
#pragma unroll
        for (int j = 0; j < 4; ++j)
            acc[i][j] = (f32x4){0.f, 0.f, 0.f, 0.f};

    for (int kt = 0; kt < K_ITERS; ++kt) {
        const int hsel = (kt >= (H_DIM / BK));   // 0: x-half, 1: h-half
        const int koff = (kt & ((H_DIM / BK) - 1)) * BK;
#pragma unroll
        for (int a = 0; a < 4; ++a)
            async_cp16(aDst[a], aSrc[a][hsel] + koff);
#pragma unroll
        for (int a = 0; a < 4; ++a)
            async_cp16(bDst[a], bSrc[a] + kt * BK);
        __syncthreads();   // drains vmcnt(0)

#pragma unroll
        for (int s = 0; s < 2; ++s) {
            bf16x8 av[4], bv[4];
#pragma unroll
            for (int i = 0; i < 4; ++i) {
                const int r  = aRow[i];
                const int ch = (s * 4 + quad) ^ (r & 7);
                av[i] = *(const bf16x8*)((const char*)&As[0][0] + r * (BK * 2) + ch * 16);
            }
#pragma unroll
            for (int j = 0; j < 4; ++j) {
                const int r  = bRow[j];
                const int ch = (s * 4 + quad) ^ (r & 7);
                bv[j] = *(const bf16x8*)((const char*)&Bs[0][0] + r * (BK * 2) + ch * 16);
            }
#pragma unroll
            for (int i = 0; i < 4; ++i)
#pragma unroll
                for (int j = 0; j < 4; ++j)
                    acc[i][j] = __builtin_amdgcn_mfma_f32_16x16x32_bf16(
                        av[i], bv[j], acc[i][j], 0, 0, 0);
        }
        __syncthreads();
    }

    // ---- epilogue: per-lane LSTM combine (j-tile == gate) ----
    const int col = n0 + wc * 16 + l16;
    const float vbi = pbi[col];
    const float vbf = pbf[col];
    const float vbo = pbo[col];
    const float vbg = pbg[col];
    const size_t HB = (size_t)B_DIM * H_DIM;
#pragma unroll
    for (int i = 0; i < 4; ++i) {
        const int mb = m_base + wr * 64 + i * 16 + quad * 4;
#pragma unroll
        for (int r = 0; r < 4; ++r) {
            const size_t m = (size_t)(mb + r);
            const float ip = acc[i][0][r] + vbi;
            const float fp = acc[i][1][r] + vbf;
            const float op = acc[i][2][r] + vbo;
            const float gp = acc[i][3][r] + vbg;
            const float ig = 1.f / (1.f + __expf(-ip));
            const float fg = 1.f / (1.f + __expf(-fp));
            const float og = 1.f / (1.f + __expf(-op));
            const float eg = __expf(-2.f * fabsf(gp));
            const float gg = copysignf((1.f - eg) / (1.f + eg), gp);
            const float cin = c[m * H_DIM + col];
            const float ct = fg * cin + ig * gg;
            const float ec = __expf(-2.f * fabsf(ct));
            const float tc = copysignf((1.f - ec) / (1.f + ec), ct);
            out[m * H_DIM + col]      = og * tc;
            out[HB + m * H_DIM + col] = ct;
        }
    }
}

// ---------------- fallback: fused fp32-load path (small ws) ----------------
__global__ __launch_bounds__(256, 2)
void lstm_gemm_fused(const float* __restrict__ x, const float* __restrict__ h,
                     const float* __restrict__ Wi, const float* __restrict__ Wf,
                     const float* __restrict__ Wo, const float* __restrict__ Wg,
                     const float* __restrict__ c,
                     const float* __restrict__ pbi, const float* __restrict__ pbf,
                     const float* __restrict__ pbo, const float* __restrict__ pbg,
                     float* __restrict__ out)
{
    __shared__ __hip_bfloat16 As[BM][BK];
    __shared__ __hip_bfloat16 Bs[BM][BK];

    const int tid  = threadIdx.x;
    const int lane = tid & 63;
    const int wave = tid >> 6;
    const int wr   = wave >> 1;
    const int wc   = wave & 1;
    const int quad = lane >> 4;
    const int l16  = lane & 15;

    const int m_base = blockIdx.y * BM;
    const int n0     = blockIdx.x * BNC;

    const int srow = tid >> 1;
    const int scol = (tid & 1) * 32;
    const float* aS[2] = {
        x + (size_t)(m_base + srow) * H_DIM + scol,
        h + (size_t)(m_base + srow) * H_DIM + scol
    };
    const int gate = (srow >> 4) & 3;
    const int grow = n0 + ((srow >> 6) << 4) + (srow & 15);
    const float* Wsel = (gate == 0) ? Wi : (gate == 1) ? Wf : (gate == 2) ? Wo : Wg;
    const float* bS = Wsel + (size_t)grow * C_DIM + scol;

    int aRow[4], bRow[4];
#pragma unroll
    for (int i = 0; i < 4; ++i) aRow[i] = wr * 64 + i * 16 + l16;
#pragma unroll
    for (int j = 0; j < 4; ++j) bRow[j] = wc * 64 + j * 16 + l16;

    f32x4 acc[4][4];
#pragma unroll
    for (int i = 0; i < 4; ++i)
#pragma unroll
        for (int j = 0; j < 4; ++j)
            acc[i][j] = (f32x4){0.f, 0.f, 0.f, 0.f};

    for (int kt = 0; kt < K_ITERS; ++kt) {
        const int hsel = (kt >= (H_DIM / BK));
        const int koff = (kt & ((H_DIM / BK) - 1)) * BK;
        const float* ap = aS[hsel] + koff;
        const float* bp = bS + kt * BK;
        __hip_bfloat16 ta[32], tb[32];
#pragma unroll
        for (int q = 0; q < 8; ++q) {
            f32x4 a = *(const f32x4*)(ap + q * 4);
            f32x4 b = *(const f32x4*)(bp + q * 4);
            ta[q*4+0]=__float2bfloat16(a[0]); ta[q*4+1]=__float2bfloat16(a[1]);
            ta[q*4+2]=__float2bfloat16(a[2]); ta[q*4+3]=__float2bfloat16(a[3]);
            tb[q*4+0]=__float2bfloat16(b[0]); tb[q*4+1]=__float2bfloat16(b[1]);
            tb[q*4+2]=__float2bfloat16(b[2]); tb[q*4+3]=__float2bfloat16(b[3]);
        }
#pragma unroll
        for (int q = 0; q < 4; ++q) {
            const int ch  = (scol / 8) + q;
            const int sl  = ch ^ (srow & 7);
            *(bf16x8*)((char*)&As[0][0] + srow * (BK * 2) + sl * 16) = *(const bf16x8*)&ta[q * 8];
            *(bf16x8*)((char*)&Bs[0][0] + srow * (BK * 2) + sl * 16) = *(const bf16x8*)&tb[q * 8];
        }
        __syncthreads();

#pragma unroll
        for (int s = 0; s < 2; ++s) {
            bf16x8 av[4], bv[4];
#pragma unroll
            for (int i = 0; i < 4; ++i) {
                const int r  = aRow[i];
                const int ch = (s * 4 + quad) ^ (r & 7);
                av[i] = *(const bf16x8*)((const char*)&As[0][0] + r * (BK * 2) + ch * 16);
            }
#pragma unroll
            for (int j = 0; j < 4; ++j) {
                const int r  = bRow[j];
                const int ch = (s * 4 + quad) ^ (r & 7);
                bv[j] = *(const bf16x8*)((const char*)&Bs[0][0] + r * (BK * 2) + ch * 16);
            }
#pragma unroll
            for (int i = 0; i < 4; ++i)
#pragma unroll
                for (int j = 0; j < 4; ++j)
                    acc[i][j] = __builtin_amdgcn_mfma_f32_16x16x32_bf16(
                        av[i], bv[j], acc[i][j], 0, 0, 0);
        }
        __syncthreads();
    }

    const int col = n0 + wc * 16 + l16;
    const float vbi = pbi[col];
    const float vbf = pbf[col];
    const float vbo = pbo[col];
    const float vbg = pbg[col];
    const size_t HB = (size_t)B_DIM * H_DIM;
#pragma unroll
    for (int i = 0; i < 4; ++i) {
        const int mb = m_base + wr * 64 + i * 16 + quad * 4;
#pragma unroll
        for (int r = 0; r < 4; ++r) {
            const size_t m = (size_t)(mb + r);
            const float ip = acc[i][0][r] + vbi;
            const float fp = acc[i][1][r] + vbf;
            const float op = acc[i][2][r] + vbo;
            const float gp = acc[i][3][r] + vbg;
            const float ig = 1.f / (1.f + __expf(-ip));
            const float fg = 1.f / (1.f + __expf(-fp));
            const float og = 1.f / (1.f + __expf(-op));
            const float eg = __expf(-2.f * fabsf(gp));
            const float gg = copysignf((1.f - eg) / (1.f + eg), gp);
            const float cin = c[m * H_DIM + col];
            const float ct = fg * cin + ig * gg;
            const float ec = __expf(-2.f * fabsf(ct));
            const float tc = copysignf((1.f - ec) / (1.f + ec), ct);
            out[m * H_DIM + col]      = og * tc;
            out[HB + m * H_DIM + col] = ct;
        }
    }
}

extern "C" void kernel_launch(void* const* d_in, const int* in_sizes, int n_in,
                              void* d_out, int out_size, void* d_ws, size_t ws_size,
                              hipStream_t stream) {
    const float* x  = (const float*)d_in[0];
    const float* h  = (const float*)d_in[1];
    const float* c  = (const float*)d_in[2];
    const float* Wi = (const float*)d_in[3];
    const float* Wf = (const float*)d_in[4];
    const float* Wo = (const float*)d_in[5];
    const float* Wg = (const float*)d_in[6];
    const float* bi = (const float*)d_in[7];
    const float* bfp= (const float*)d_in[8];
    const float* bo = (const float*)d_in[9];
    const float* bg = (const float*)d_in[10];
    float* out = (float*)d_out;

    dim3 grid(H_DIM / BNC, B_DIM / BM);  // (32, 64) = 2048 blocks

    if (ws_size >= WS_NEEDED) {
        __hip_bfloat16* wsb = (__hip_bfloat16*)d_ws;
        cvt_kernel<<<CVT_TOTAL / 4 / 256, 256, 0, stream>>>(x, h, Wi, Wf, Wo, Wg, wsb);
        lstm_gemm_bf16<<<grid, dim3(256), 0, stream>>>(
            wsb, wsb + XH_ELEMS, wsb + 2 * (size_t)XH_ELEMS,
            c, bi, bfp, bo, bg, out);
    } else {
        lstm_gemm_fused<<<grid, dim3(256), 0, stream>>>(
            x, h, Wi, Wf, Wo, Wg, c, bi, bfp, bo, bg, out);
    }
}